// Round 1
// 880.758 us; speedup vs baseline: 1.2864x; 1.2864x over previous
//
#include <hip/hip_runtime.h>
#include <stdint.h>

#define N_TOK 16384
#define DIM   2048
#define NEXP  8

#define NTILES 136      // max ceil-padded-256 M-tiles: <=135, rounded up
#define NSLOTS 36864    // 144*256 >= 32768 + 8*255

typedef __bf16 bf16x8 __attribute__((ext_vector_type(8)));
typedef float  f32x4  __attribute__((ext_vector_type(4)));

__device__ __forceinline__ unsigned short f2bf(float f) {
    union { float f; uint32_t u; } v; v.f = f;
    uint32_t u = v.u;
    u += 0x7fffu + ((u >> 16) & 1u);   // round-to-nearest-even
    return (unsigned short)(u >> 16);
}

// ---------------------------------------------------------------------------
// Transpose + convert expert weights: W[e][k][n] fp32 -> Wt[e][n][k] bf16.
__global__ __launch_bounds__(256) void wconv_kernel(
    const float* __restrict__ W, unsigned short* __restrict__ Wt)
{
    __shared__ float tile[64][65];        // +1 pad: conflict-free column reads
    int e  = blockIdx.z;
    int kt = blockIdx.y * 64, nt = blockIdx.x * 64;
    int r4 = threadIdx.x >> 4;            // 0..15
    int c4 = threadIdx.x & 15;            // 0..15
    const float* src = W + ((size_t)e * DIM + kt) * DIM + nt;
#pragma unroll
    for (int i = 0; i < 4; ++i) {
        int r = i * 16 + r4;
        float4 v = *(const float4*)(src + (size_t)r * DIM + c4 * 4);
        tile[r][c4 * 4 + 0] = v.x; tile[r][c4 * 4 + 1] = v.y;
        tile[r][c4 * 4 + 2] = v.z; tile[r][c4 * 4 + 3] = v.w;
    }
    __syncthreads();
    unsigned short* dst = Wt + ((size_t)e * DIM + nt) * DIM + kt;
#pragma unroll
    for (int i = 0; i < 4; ++i) {
        int n = i * 16 + r4;
        ushort4 h;
        h.x = f2bf(tile[c4 * 4 + 0][n]);
        h.y = f2bf(tile[c4 * 4 + 1][n]);
        h.z = f2bf(tile[c4 * 4 + 2][n]);
        h.w = f2bf(tile[c4 * 4 + 3][n]);
        *(ushort4*)(dst + (size_t)n * DIM + c4 * 4) = h;
    }
}

// ---------------------------------------------------------------------------
// Gate: one wave per token. Computes logits = x @ gate_w, top-2 + softmax,
// and fuses the fp32->bf16 conversion of the token row into ws.
__global__ __launch_bounds__(256) void gate_kernel(
    const float* __restrict__ X, const float* __restrict__ GW,
    unsigned short* __restrict__ Abf, int* __restrict__ tokE,
    float* __restrict__ tokW)
{
    int wave = threadIdx.x >> 6, lane = threadIdx.x & 63;
    int t = blockIdx.x * 4 + wave;
    const float4* xrow = (const float4*)(X + (size_t)t * DIM);
    float acc[NEXP];
#pragma unroll
    for (int e = 0; e < NEXP; ++e) acc[e] = 0.f;
#pragma unroll
    for (int i = 0; i < 8; ++i) {
        int d4 = i * 64 + lane;           // float4 index within the row
        float4 x = xrow[d4];
        ushort4 h;
        h.x = f2bf(x.x); h.y = f2bf(x.y); h.z = f2bf(x.z); h.w = f2bf(x.w);
        *(ushort4*)(Abf + (size_t)t * DIM + (size_t)d4 * 4) = h;
        const float* g = GW + (size_t)d4 * 4 * NEXP;
#pragma unroll
        for (int e = 0; e < NEXP; ++e)
            acc[e] += x.x * g[e] + x.y * g[NEXP + e]
                    + x.z * g[2 * NEXP + e] + x.w * g[3 * NEXP + e];
    }
#pragma unroll
    for (int off = 32; off >= 1; off >>= 1)
#pragma unroll
        for (int e = 0; e < NEXP; ++e)
            acc[e] += __shfl_down(acc[e], off, 64);
    if (lane == 0) {
        int i0 = 0;
#pragma unroll
        for (int e = 1; e < NEXP; ++e) if (acc[e] > acc[i0]) i0 = e;
        int i1 = (i0 == 0) ? 1 : 0;
#pragma unroll
        for (int e = 0; e < NEXP; ++e)
            if (e != i0 && acc[e] > acc[i1]) i1 = e;
        float e1 = expf(acc[i1] - acc[i0]);
        float s  = 1.f + e1;
        tokE[2 * t]     = i0;  tokE[2 * t + 1] = i1;
        tokW[2 * t]     = 1.f / s;
        tokW[2 * t + 1] = e1 / s;
    }
}

// ---------------------------------------------------------------------------
// Per-expert counts via LDS histogram (8 global atomics per block).
__global__ __launch_bounds__(256) void count_kernel(
    const int* __restrict__ tokE, int* __restrict__ counts)
{
    __shared__ int lc[NEXP];
    if (threadIdx.x < NEXP) lc[threadIdx.x] = 0;
    __syncthreads();
#pragma unroll
    for (int p = 0; p < 2; ++p) {
        int i = blockIdx.x * 512 + p * 256 + threadIdx.x;
        atomicAdd(&lc[tokE[i]], 1);
    }
    __syncthreads();
    if (threadIdx.x < NEXP) atomicAdd(&counts[threadIdx.x], lc[threadIdx.x]);
}

// Prefix-sum of 256-padded segments + static tile map (single thread, E=8).
__global__ void setup_kernel(const int* __restrict__ counts, int* __restrict__ off,
                             int* __restrict__ tile_e, int* __restrict__ tile_s0)
{
    if (threadIdx.x != 0 || blockIdx.x != 0) return;
    int o = 0, ti = 0;
    for (int e = 0; e < NEXP; ++e) {
        off[e] = o;
        int pc = (counts[e] + 255) & ~255;
        for (int m = 0; m < pc; m += 256) { tile_e[ti] = e; tile_s0[ti] = o + m; ++ti; }
        o += pc;
    }
    for (; ti < NTILES; ++ti) tile_e[ti] = -1;
}

__global__ __launch_bounds__(256) void initperm_kernel(
    int* __restrict__ perm, float* __restrict__ pw)
{
    int i = blockIdx.x * 256 + threadIdx.x;   // grid 144 -> 36864 slots
    perm[i] = -1;
    pw[i]   = 0.f;
}

// Slot assignment: block-aggregated ranks, then one global cursor bump per
// expert per block.
__global__ __launch_bounds__(256) void assign_kernel(
    const int* __restrict__ tokE, const float* __restrict__ tokW,
    const int* __restrict__ off, int* __restrict__ cursors,
    int* __restrict__ perm, float* __restrict__ pw)
{
    __shared__ int lc[NEXP], lb[NEXP];
    if (threadIdx.x < NEXP) lc[threadIdx.x] = 0;
    __syncthreads();
    int mye[2], myr[2];
#pragma unroll
    for (int p = 0; p < 2; ++p) {
        int i = blockIdx.x * 512 + p * 256 + threadIdx.x;
        mye[p] = tokE[i];
        myr[p] = atomicAdd(&lc[mye[p]], 1);
    }
    __syncthreads();
    if (threadIdx.x < NEXP) lb[threadIdx.x] = atomicAdd(&cursors[threadIdx.x], lc[threadIdx.x]);
    __syncthreads();
#pragma unroll
    for (int p = 0; p < 2; ++p) {
        int i = blockIdx.x * 512 + p * 256 + threadIdx.x;
        int slot = off[mye[p]] + lb[mye[p]] + myr[p];
        perm[slot] = i >> 1;          // token id (pairs are 2t, 2t+1)
        pw[slot]   = tokW[i];
    }
}

// ---------------------------------------------------------------------------
// Gathered GEMM, 256x256 tile, BK=64, 8 waves, double-buffered LDS with
// 2-phase prefetch (T3 minimum): stage K-tile t+1 BEFORE computing K-tile t,
// one barrier per K-tile. The vmcnt(0) drain at the barrier then lands
// ~64 MFMA (~700 cy) after issue instead of immediately after (the m97
// structure's exposed-latency stall).
// XOR bank swizzle preserved from previous version (0 measured conflicts):
// LDS[row][chunk] holds source k-chunk  chunk ^ (row&7); staging lane
// fetches global chunk (lane&7)^(lane>>3) since row&7 == lane>>3.
#define GLD16(gptr, lptr) __builtin_amdgcn_global_load_lds( \
    (const __attribute__((address_space(1))) void*)(gptr),  \
    (__attribute__((address_space(3))) void*)(lptr), 16, 0, 0)

#define MOE_LDS_BYTES (4 * 256 * 64 * 2 + 256 * 4 + 256 * 4)  // 133120

__global__ __launch_bounds__(512, 2) void moe_gemm(
    const unsigned short* __restrict__ A,   // bf16 [N][D]
    const unsigned short* __restrict__ Bt,  // bf16 [E][n][k]
    const float* __restrict__ bias,         // fp32 [E][D]
    const int* __restrict__ perm, const float* __restrict__ pw,
    const int* __restrict__ tile_e, const int* __restrict__ tile_s0,
    float* __restrict__ out)
{
    extern __shared__ unsigned short lds[];
    unsigned short* AsB = lds;                   // [2][256][64] bf16
    unsigned short* BsB = lds + 2 * 256 * 64;    // [2][256][64] bf16
    int*   toks = (int*)(lds + 4 * 256 * 64);    // [256]
    float* tws  = (float*)(toks + 256);          // [256]

    int e = tile_e[blockIdx.y];
    if (e < 0) return;
    int s0 = tile_s0[blockIdx.y];
    int n0 = blockIdx.x * 256;

    int tid = threadIdx.x, wave = tid >> 6, lane = tid & 63;

    if (tid < 256) {
        int t = perm[s0 + tid];
        toks[tid] = (t < 0) ? 0 : t;
        tws[tid]  = (t < 0) ? 0.f : pw[s0 + tid];
    }
    __syncthreads();

    // Staging bases: round r covers rows r*64 + wave*8 + (lane>>3).
    int kof = (((lane & 7) ^ (lane >> 3)) * 8);    // pre-swizzled source chunk
    const unsigned short* ab[4];
    const unsigned short* bb[4];
#pragma unroll
    for (int r = 0; r < 4; ++r) {
        int row = r * 64 + wave * 8 + (lane >> 3);     // 0..255
        ab[r] = A + (size_t)toks[row] * DIM + kof;     // gathered token row
        bb[r] = Bt + ((size_t)e * DIM + n0 + row) * DIM + kof;
    }

    f32x4 acc[8][4] = {};
    int wr = wave >> 2, wc = wave & 3;      // 2M x 4N wave grid
    int wm = wr * 128, wn = wc * 64;        // per-wave 128x64 output
    int fr = lane & 15;                     // fragment m/n index
    int q  = lane >> 4;                     // fragment k quarter
    int rx = fr & 7;                        // row&7 of fragment rows read

#define STAGE(buf, k0) do {                                              \
    _Pragma("unroll")                                                    \
    for (int r = 0; r < 4; ++r) {                                        \
        int cb = ((buf) * 16384 + (r * 64 + wave * 8) * 64) * 2;         \
        GLD16(ab[r] + (k0), (char*)AsB + cb);                            \
        GLD16(bb[r] + (k0), (char*)BsB + cb);                            \
    } } while (0)

    STAGE(0, 0);
    __syncthreads();               // drain prologue tile

    int cur = 0;
    for (int t = 0; t < DIM / 64; ++t) {
        if (t + 1 < DIM / 64) STAGE(cur ^ 1, (t + 1) * 64);   // prefetch next
        const unsigned short* Ab = AsB + cur * 16384;
        const unsigned short* Bb = BsB + cur * 16384;
#pragma unroll
        for (int kk = 0; kk < 64; kk += 32) {
            int p = (((kk >> 3) + q) ^ rx) * 8;               // swizzled pos
            bf16x8 af[8], bfr[4];
#pragma unroll
            for (int i = 0; i < 8; ++i)
                af[i] = *(const bf16x8*)(Ab + (wm + i * 16 + fr) * 64 + p);
#pragma unroll
            for (int j = 0; j < 4; ++j)
                bfr[j] = *(const bf16x8*)(Bb + (wn + j * 16 + fr) * 64 + p);
#pragma unroll
            for (int i = 0; i < 8; ++i)
#pragma unroll
                for (int j = 0; j < 4; ++j)
                    acc[i][j] = __builtin_amdgcn_mfma_f32_16x16x32_bf16(
                        af[i], bfr[j], acc[i][j], 0, 0, 0);
        }
        __syncthreads();           // one barrier/K-tile: drains prefetch +
        cur ^= 1;                  // protects buffer about to be re-staged
    }

    // Epilogue: C/D mapping col=lane&15, row=(lane>>4)*4+r (m89-verified).
    int rq = (lane >> 4) * 4;
    float bv[4];
#pragma unroll
    for (int j = 0; j < 4; ++j)
        bv[j] = bias[e * DIM + n0 + wn + j * 16 + fr];
#pragma unroll
    for (int i = 0; i < 8; ++i) {
#pragma unroll
        for (int r = 0; r < 4; ++r) {
            int mrow = wm + i * 16 + rq + r;
            float w = tws[mrow];
            if (w != 0.f) {
                float* orow = out + (size_t)toks[mrow] * DIM + n0 + wn;
#pragma unroll
                for (int j = 0; j < 4; ++j)
                    atomicAdd(orow + j * 16 + fr, w * (acc[i][j][r] + bv[j]));
            }
        }
    }
#undef STAGE
}

// ---------------------------------------------------------------------------
extern "C" void kernel_launch(void* const* d_in, const int* in_sizes, int n_in,
                              void* d_out, int out_size, void* d_ws, size_t ws_size,
                              hipStream_t stream)
{
    const float* X  = (const float*)d_in[0];   // [N][D]
    const float* GW = (const float*)d_in[1];   // [D][E]
    const float* W  = (const float*)d_in[2];   // [E][D][D]
    const float* Bb = (const float*)d_in[3];   // [E][D]
    float* out = (float*)d_out;

    char* ws = (char*)d_ws;
    unsigned short* Abf = (unsigned short*)ws;                 // 64 MiB bf16 A
    unsigned short* Wt  = (unsigned short*)(ws + 67108864);    // 64 MiB bf16 B^T
    char* ctrl = ws + 134217728;
    int*   counts  = (int*)(ctrl + 0);
    int*   cursors = (int*)(ctrl + 64);
    int*   off     = (int*)(ctrl + 128);
    int*   tile_e  = (int*)(ctrl + 256);
    int*   tile_s0 = (int*)(ctrl + 2048);
    int*   tokE    = (int*)(ctrl + 4096);      // 32768 ints
    float* tokW    = (float*)(ctrl + 135168);  // 32768 floats
    int*   perm    = (int*)(ctrl + 266240);    // 36864 ints
    float* pw      = (float*)(ctrl + 413696);  // 36864 floats (end 561152)

    static bool attr_set = false;
    if (!attr_set) {
        hipFuncSetAttribute(reinterpret_cast<const void*>(moe_gemm),
                            hipFuncAttributeMaxDynamicSharedMemorySize,
                            MOE_LDS_BYTES);
        attr_set = true;
    }

    hipMemsetAsync(d_out, 0, (size_t)N_TOK * DIM * sizeof(float), stream);
    hipMemsetAsync(ctrl, 0, 128, stream);   // counts + cursors

    wconv_kernel <<<dim3(32, 32, NEXP), 256, 0, stream>>>(W, Wt);
    gate_kernel  <<<dim3(N_TOK / 4),    256, 0, stream>>>(X, GW, Abf, tokE, tokW);
    count_kernel <<<dim3(64),           256, 0, stream>>>(tokE, counts);
    setup_kernel <<<dim3(1),             64, 0, stream>>>(counts, off, tile_e, tile_s0);
    initperm_kernel<<<dim3(144),        256, 0, stream>>>(perm, pw);
    assign_kernel<<<dim3(64),           256, 0, stream>>>(tokE, tokW, off, cursors, perm, pw);
    moe_gemm     <<<dim3(8, NTILES), 512, MOE_LDS_BYTES, stream>>>(
        Abf, Wt, Bb, perm, pw, tile_e, tile_s0, out);
}